// Round 8
// baseline (15660.008 us; speedup 1.0000x reference)
//
#include <hip/hip_runtime.h>
#include <hip/hip_fp16.h>

#define TT 500
#define HH 512
#define TWOH 1024

typedef _Float16 f16x8 __attribute__((ext_vector_type(8)));
typedef float f32x4 __attribute__((ext_vector_type(4)));

__global__ void prep_kernel(const float* __restrict__ u,
                            __half* __restrict__ u16) {
  int i = blockIdx.x * blockDim.x + threadIdx.x;
  if (i < TWOH * HH) u16[i] = __float2half(u[i]);
}

#define LDB(BA, BZ, kb)                                                        \
  _Pragma("unroll") for (int nt = 0; nt < 4; ++nt) {                           \
    BA[nt] = *(const f16x8*)(uA[nt] + (kb) * 32);                              \
    BZ[nt] = *(const f16x8*)(uZ[nt] + (kb) * 32);                              \
  }

#define LDA(DST, PAR, kb)                                                      \
  DST = *(const f16x8*)(&h16[PAR][0] +                                         \
                        ((l15 * 1024 + (kb) * 64 + q * 16) ^ ((l15 & 7) << 4)));

#define MM(A, BA, BZ)                                                          \
  _Pragma("unroll") for (int nt = 0; nt < 4; ++nt) {                           \
    accA[nt] =                                                                 \
        __builtin_amdgcn_mfma_f32_16x16x32_f16(A, BA[nt], accA[nt], 0, 0, 0);  \
    accZ[nt] =                                                                 \
        __builtin_amdgcn_mfma_f32_16x16x32_f16(A, BZ[nt], accZ[nt], 0, 0, 0);  \
  }

// 8 blocks x 512 threads. Block = group g (16 batch rows), fully
// self-contained on one CU: zero inter-block communication, no atomics,
// no polling. Wave w owns h-cols [w*64, w*64+64): at-gate cols same range,
// zt-gate cols +512, so h_new is computed fully in-lane.
// Lane (l15,q): acc element (m=4q+r, col=j0+nt*16+l15), nt=0..3, r=0..3.
__global__ __launch_bounds__(512, 2) void ligru_solo(
    const float* __restrict__ wx, const __half* __restrict__ u16,
    const float* __restrict__ ht, const float* __restrict__ mask,
    float* __restrict__ out) {
  const int tid = threadIdx.x;
  const int lane = tid & 63;
  const int w = tid >> 6;   // 0..7
  const int l15 = lane & 15;
  const int q = lane >> 4;  // 0..3
  const int g = blockIdx.x; // 0..7
  const int row0 = g * 16;
  const int j0 = w * 64;

  __shared__ alignas(16) char h16[2][16384];  // [par][m][k] fp16, XOR-swz

  // ---- stage h0 into parity 0 (thread covers 16 halves of one row)
  {
    const int m = tid >> 5;
    const int k0 = (tid & 31) * 16;
    const float* src = ht + (size_t)(row0 + m) * HH + k0;
    __half tmp[16];
#pragma unroll
    for (int i = 0; i < 16; ++i) tmp[i] = __float2half(src[i]);
    const int swz = (m & 7) << 4;
    char* base = &h16[0][0];
    *(uint4*)(base + ((m * 1024 + k0 * 2) ^ swz)) = *(uint4*)&tmp[0];
    *(uint4*)(base + ((m * 1024 + k0 * 2 + 16) ^ swz)) = *(uint4*)&tmp[8];
  }

  // ---- persistent per-lane state: fp32 master h + mask
  float hmst[4][4], msk[4][4];  // [nt][r]
#pragma unroll
  for (int nt = 0; nt < 4; ++nt)
#pragma unroll
    for (int r = 0; r < 4; ++r) {
      size_t off = (size_t)(row0 + 4 * q + r) * HH + j0 + nt * 16 + l15;
      msk[nt][r] = mask[off];
      hmst[nt][r] = ht[off];
    }

  // ---- per-lane u16 base pointers (B-frags streamed from L2 each step)
  const __half* uA[4];
  const __half* uZ[4];
#pragma unroll
  for (int nt = 0; nt < 4; ++nt) {
    int jc = j0 + nt * 16 + l15;
    uA[nt] = u16 + (size_t)jc * HH + q * 8;
    uZ[nt] = u16 + (size_t)(HH + jc) * HH + q * 8;
  }

  const size_t BTH = (size_t)128 * TT * HH;
  float* out_h = out;
  float* out_z = out + BTH;
  float* out_a = out + 2 * BTH;
  float* out_hc = out + 3 * BTH;

  __syncthreads();

  for (int t = 0; t < TT; ++t) {
    const int par = t & 1;

    // wx loads issued up front; consumed ~5000 cyc later in the epilogue
    float wxa[4][4], wxz[4][4];
#pragma unroll
    for (int nt = 0; nt < 4; ++nt)
#pragma unroll
      for (int r = 0; r < 4; ++r) {
        size_t base =
            ((size_t)(row0 + 4 * q + r) * TT + t) * TWOH + j0 + nt * 16 + l15;
        wxa[nt][r] = __builtin_nontemporal_load(wx + base);
        wxz[nt][r] = __builtin_nontemporal_load(wx + base + HH);
      }

    f32x4 accA[4], accZ[4];
#pragma unroll
    for (int nt = 0; nt < 4; ++nt) {
      accA[nt] = (f32x4){0.f, 0.f, 0.f, 0.f};
      accZ[nt] = (f32x4){0.f, 0.f, 0.f, 0.f};
    }

    // ---- k-loop: 16 k-steps, 1-deep manual double buffer for B (L2) and
    // A (LDS). 8 MFMA per k-step per wave, all to independent accumulators.
    f16x8 bA0[4], bZ0[4], bA1[4], bZ1[4], a0, a1;
    LDB(bA0, bZ0, 0)
    LDA(a0, par, 0)
#pragma unroll
    for (int kb = 0; kb < 16; kb += 2) {
      LDB(bA1, bZ1, kb + 1)
      LDA(a1, par, kb + 1)
      MM(a0, bA0, bZ0)
      if (kb + 2 < 16) {
        LDB(bA0, bZ0, kb + 2)
        LDA(a0, par, kb + 2)
      }
      MM(a1, bA1, bZ1)
    }

    // ---- epilogue: gates -> h_new -> LDS (next step's A), outputs async
    const int parn = par ^ 1;
    char* hdst = &h16[parn][0];
#pragma unroll
    for (int nt = 0; nt < 4; ++nt)
#pragma unroll
      for (int r = 0; r < 4; ++r) {
        const int m = 4 * q + r;
        const int jc = j0 + nt * 16 + l15;
        float at = accA[nt][r] + wxa[nt][r];
        float ztp = accZ[nt][r] + wxz[nt][r];
        float zt = 1.f / (1.f + __expf(-ztp));
        float hc = fmaxf(at, 0.f) * msk[nt][r];
        float hn = zt * (hmst[nt][r] - hc) + hc;  // = h*zt + (1-zt)*hc
        hmst[nt][r] = hn;
        *(__half*)(hdst + ((m * 1024 + jc * 2) ^ ((m & 7) << 4))) =
            __float2half(hn);
        size_t oi = ((size_t)(row0 + m) * TT + t) * HH + jc;
        __builtin_nontemporal_store(hn, out_h + oi);
        __builtin_nontemporal_store(zt, out_z + oi);
        __builtin_nontemporal_store(at, out_a + oi);
        __builtin_nontemporal_store(hc, out_hc + oi);
      }
    __syncthreads();  // h16[parn] complete -> next step may read it
  }
}

extern "C" void kernel_launch(void* const* d_in, const int* in_sizes, int n_in,
                              void* d_out, int out_size, void* d_ws,
                              size_t ws_size, hipStream_t stream) {
  const float* wx = (const float*)d_in[0];
  const float* u = (const float*)d_in[1];
  const float* ht = (const float*)d_in[2];
  const float* mask = (const float*)d_in[3];
  float* out = (float*)d_out;

  __half* u16 = (__half*)d_ws;  // 1 MiB

  hipLaunchKernelGGL(prep_kernel, dim3((TWOH * HH + 255) / 256), dim3(256), 0,
                     stream, u, u16);
  hipLaunchKernelGGL(ligru_solo, dim3(8), dim3(512), 0, stream, wx, u16, ht,
                     mask, out);
}

// Round 9
// 4167.390 us; speedup vs baseline: 3.7577x; 3.7577x over previous
//
#include <hip/hip_runtime.h>
#include <hip/hip_fp16.h>

#define BB 128
#define TT 500
#define HH 512
#define TWOH 1024
#define KB 16  // k-tiles of 32

typedef _Float16 f16x8 __attribute__((ext_vector_type(8)));
typedef float f32x4 __attribute__((ext_vector_type(4)));
typedef unsigned long long u64;

// ws: u16 1 MiB | hx u32 [8 g][2 par][16 m][512 k] (512 KiB)
// hx word = (tag16 << 16) | fp16 h[m][k]   (tag = step, 0..500; 0xFFFF = inv)
#define WS_U16_HALVES (TWOH * HH)
#define HX_WORDS (8 * 2 * 16 * HH)

__global__ void prep_kernel(const float* __restrict__ u,
                            const float* __restrict__ ht,
                            __half* __restrict__ u16,
                            unsigned* __restrict__ hx) {
  int i = blockIdx.x * blockDim.x + threadIdx.x;
  if (i < WS_U16_HALVES) u16[i] = __float2half(u[i]);
  if (i < HX_WORDS) {
    int g = i >> 14, rem = i & 16383;
    int par = rem >> 13, m = (rem >> 9) & 15, k = rem & 511;
    unsigned val;
    if (par == 0) {  // h_0, tag 0 in high halfword
      int R = g * 16 + m;
      val = (unsigned)__half_as_ushort(__float2half(ht[(size_t)R * HH + k]));
    } else {
      val = 0xFFFF0000u;  // sentinel (never matches; replay-stale safe)
    }
    hx[i] = val;
  }
}

#define TAGMASK 0xFFFF0000FFFF0000ull

// Tagged cooperative read: thread tid owns qword tid of each of 16 rows.
// Each dword self-validates (tag in high halfword, fp16 payload in low).
#define CHECK_RETRY(QW, GIDX, PARC, TCUR)                                      \
  {                                                                            \
    const u64* _src = (const u64*)hx + ((size_t)((GIDX)*2 + (PARC)) << 12) + tid; \
    const u64 _tagp = ((u64)(unsigned)(TCUR) << 48) | ((u64)(unsigned)(TCUR) << 16); \
    bool _ok = true;                                                           \
    _Pragma("unroll") for (int pp = 0; pp < 16; ++pp)                          \
        _ok &= ((QW[pp] & TAGMASK) == _tagp);                                  \
    int _bail = 0;                                                             \
    while (!__all(_ok)) {                                                      \
      __builtin_amdgcn_s_sleep(1);                                             \
      _Pragma("unroll") for (int pp = 0; pp < 16; ++pp)                        \
          QW[pp] = __hip_atomic_load(_src + pp * 256, __ATOMIC_RELAXED,        \
                                     __HIP_MEMORY_SCOPE_AGENT);                \
      _ok = true;                                                              \
      _Pragma("unroll") for (int pp = 0; pp < 16; ++pp)                        \
          _ok &= ((QW[pp] & TAGMASK) == _tagp);                                \
      if (++_bail > (1 << 15)) break;                                          \
    }                                                                          \
  }

#define PREFETCH(QW, GIDX, PARN)                                               \
  {                                                                            \
    const u64* _srcn = (const u64*)hx + ((size_t)((GIDX)*2 + (PARN)) << 12) + tid; \
    _Pragma("unroll") for (int pp = 0; pp < 16; ++pp)                          \
        QW[pp] = __hip_atomic_load(_srcn + pp * 256, __ATOMIC_RELAXED,         \
                                   __HIP_MEMORY_SCOPE_AGENT);                  \
  }

// One phase: chain C at step TCUR consuming buffer QWc; prefetch buffer QWp
// for chain (C+2)&3 at step TPF (issued 2 phases before ITS use).
#define PHASE(C, QWc, QWp, TCUR, TPF)                                          \
  {                                                                            \
    /* wx for this chain/phase, issued before the check (h-independent) */     \
    float wxa[4], wxz[4];                                                      \
    _Pragma("unroll") for (int r = 0; r < 4; ++r) {                            \
      size_t _b = ((size_t)(row0[C] + 4 * q + r) * TT + (TCUR)) * TWOH + j;    \
      wxa[r] = wx[_b];                                                         \
      wxz[r] = wx[_b + HH];                                                    \
    }                                                                          \
    CHECK_RETRY(QWc, gI[C], ((TCUR)&1), (TCUR))                                \
    { /* stage payload halves into XOR-swizzled LDS */                         \
      char* _dst = hsm[(C)&1];                                                 \
      _Pragma("unroll") for (int pp = 0; pp < 16; ++pp) {                      \
        unsigned _d0 = (unsigned)QWc[pp], _d1 = (unsigned)(QWc[pp] >> 32);     \
        unsigned _pk = (_d0 & 0xFFFFu) | (_d1 << 16);                          \
        *(unsigned*)(_dst + ((pp * 1024 + tid * 4) ^ ((pp & 7) << 4))) = _pk;  \
      }                                                                        \
    }                                                                          \
    __syncthreads();                                                           \
    PREFETCH(QWp, gI[((C) + 2) & 3], ((TPF)&1))                                \
    f32x4 acc0 = {0.f, 0.f, 0.f, 0.f}, acc1 = {0.f, 0.f, 0.f, 0.f};           \
    _Pragma("unroll") for (int kb = 0; kb < KB; ++kb) {                        \
      int _off = (l15 * 1024 + kb * 64 + q * 16) ^ ((l15 & 7) << 4);           \
      f16x8 _af = *(const f16x8*)(hsm[(C)&1] + _off);                          \
      acc0 = __builtin_amdgcn_mfma_f32_16x16x32_f16(_af, bf[kb][0], acc0, 0, 0, 0); \
      acc1 = __builtin_amdgcn_mfma_f32_16x16x32_f16(_af, bf[kb][1], acc1, 0, 0, 0); \
    }                                                                          \
    /* epilogue: tagged per-dword h stores first, outputs after */             \
    unsigned* _hd = hx + ((size_t)(gI[C] * 2 + (((TCUR) + 1) & 1)) << 13);     \
    const unsigned _tg = (unsigned)((TCUR) + 1) << 16;                         \
    float _atv[4], _ztv[4], _hcv[4];                                           \
    _Pragma("unroll") for (int r = 0; r < 4; ++r) {                            \
      float _at = acc0[r] + wxa[r];                                            \
      float _zp = acc1[r] + wxz[r];                                            \
      float _zt = 1.f / (1.f + __expf(-_zp));                                  \
      float _hc = fmaxf(_at, 0.f) * mreg[C][r];                                \
      float _hn = hreg[C][r] * _zt + (1.f - _zt) * _hc;                        \
      hreg[C][r] = _hn;                                                        \
      __hip_atomic_store(_hd + (4 * q + r) * HH + j,                           \
                         _tg | (unsigned)__half_as_ushort(__float2half(_hn)),  \
                         __ATOMIC_RELAXED, __HIP_MEMORY_SCOPE_AGENT);          \
      _atv[r] = _at; _ztv[r] = _zt; _hcv[r] = _hc;                             \
    }                                                                          \
    _Pragma("unroll") for (int r = 0; r < 4; ++r) {                            \
      size_t _oi = ((size_t)(row0[C] + 4 * q + r) * TT + (TCUR)) * HH + j;     \
      __builtin_nontemporal_store(hreg[C][r], &out_h[_oi]);                    \
      __builtin_nontemporal_store(_ztv[r], &out_z[_oi]);                       \
      __builtin_nontemporal_store(_atv[r], &out_a[_oi]);                       \
      __builtin_nontemporal_store(_hcv[r], &out_hc[_oi]);                      \
    }                                                                          \
  }

// 16 blocks x 256 threads (4 waves). Block b: col-slice s=b&7 (64 cols, both
// gates), chain-set cs=b>>3 serving groups {4cs..4cs+3} round-robin. Fused
// tag+data h exchange (relaxed agent atomics); each chain's data prefetched
// 2 phases before use -> tag checks hit without a serial MALL round trip.
__global__ __launch_bounds__(256, 1) void ligru_mfma(
    const float* __restrict__ wx, const __half* __restrict__ u16,
    const float* __restrict__ ht, const float* __restrict__ mask,
    float* __restrict__ out, unsigned* __restrict__ hx) {
  const int tid = threadIdx.x;
  const int lane = tid & 63;
  const int w = tid >> 6;
  const int l15 = lane & 15;
  const int q = lane >> 4;
  const int b = blockIdx.x;
  const int s = b & 7;
  const int cs = b >> 3;
  const int gI[4] = {cs * 4, cs * 4 + 1, cs * 4 + 2, cs * 4 + 3};
  const int row0[4] = {gI[0] * 16, gI[1] * 16, gI[2] * 16, gI[3] * 16};
  const int j = s * 64 + w * 16 + l15;  // this lane's hidden col

  __shared__ alignas(16) char hsm[2][16 * 1024];  // staging, XOR-swizzled

  // B-frags (u), persistent (128 VGPR), shared by all 4 chains (same cols).
  f16x8 bf[KB][2];
#pragma unroll
  for (int kb = 0; kb < KB; ++kb) {
    bf[kb][0] = *(const f16x8*)(u16 + (size_t)j * HH + kb * 32 + q * 8);
    bf[kb][1] = *(const f16x8*)(u16 + (size_t)(HH + j) * HH + kb * 32 + q * 8);
  }

  // per-lane persistent state: rows m=4q+r, col j; fp32 master h
  float hreg[4][4], mreg[4][4];
#pragma unroll
  for (int C = 0; C < 4; ++C)
#pragma unroll
    for (int r = 0; r < 4; ++r) {
      size_t off = (size_t)(row0[C] + 4 * q + r) * HH + j;
      mreg[C][r] = mask[off];
      hreg[C][r] = ht[off];
    }

  const size_t BTH = (size_t)BB * TT * HH;
  float* out_h = out;
  float* out_z = out + BTH;
  float* out_a = out + 2 * BTH;
  float* out_hc = out + 3 * BTH;

  u64 qw0[16], qw1[16], qw2[16], qw3[16];
  PREFETCH(qw0, gI[0], 0)  // h(0) of chain 0: written by prep, tag 0
  PREFETCH(qw1, gI[1], 0)  // h(0) of chain 1

  for (int t = 0; t < TT; ++t) {
    PHASE(0, qw0, qw2, t, t)      // consume c0(t); prefetch c2(t)
    PHASE(1, qw1, qw3, t, t)      // consume c1(t); prefetch c3(t)
    PHASE(2, qw2, qw0, t, t + 1)  // consume c2(t); prefetch c0(t+1)
    PHASE(3, qw3, qw1, t, t + 1)  // consume c3(t); prefetch c1(t+1)
  }
}

extern "C" void kernel_launch(void* const* d_in, const int* in_sizes, int n_in,
                              void* d_out, int out_size, void* d_ws,
                              size_t ws_size, hipStream_t stream) {
  const float* wx = (const float*)d_in[0];
  const float* u = (const float*)d_in[1];
  const float* ht = (const float*)d_in[2];
  const float* mask = (const float*)d_in[3];
  float* out = (float*)d_out;

  __half* u16 = (__half*)d_ws;
  unsigned* hx = (unsigned*)(u16 + WS_U16_HALVES);

  hipLaunchKernelGGL(prep_kernel, dim3(2048), dim3(256), 0, stream, u, ht, u16,
                     hx);
  hipLaunchKernelGGL(ligru_mfma, dim3(16), dim3(256), 0, stream, wx, u16, ht,
                     mask, out, hx);
}

// Round 10
// 1416.363 us; speedup vs baseline: 11.0565x; 2.9423x over previous
//
#include <hip/hip_runtime.h>
#include <hip/hip_fp16.h>

#define BB 128
#define TT 500
#define HH 512
#define TWOH 1024
#define KB 16  // k-tiles of 32

typedef _Float16 f16x8 __attribute__((ext_vector_type(8)));
typedef float f32x4 __attribute__((ext_vector_type(4)));
typedef unsigned long long u64;

// ws: u16 1 MiB | hx u32 [8 g][2 par][16 m][512 k] (512 KiB)
// hx word = (tag16 << 16) | fp16 h[m][k]   (tag = step, 0..500; 0xFFFF = inv)
#define WS_U16_HALVES (TWOH * HH)
#define HX_WORDS (8 * 2 * 16 * HH)

__global__ void prep_kernel(const float* __restrict__ u,
                            const float* __restrict__ ht,
                            __half* __restrict__ u16,
                            unsigned* __restrict__ hx) {
  int i = blockIdx.x * blockDim.x + threadIdx.x;
  if (i < WS_U16_HALVES) u16[i] = __float2half(u[i]);
  if (i < HX_WORDS) {
    int g = i >> 14, rem = i & 16383;
    int par = rem >> 13, m = (rem >> 9) & 15, k = rem & 511;
    unsigned val;
    if (par == 0) {  // h_0, tag 0 in high halfword
      int R = g * 16 + m;
      val = (unsigned)__half_as_ushort(__float2half(ht[(size_t)R * HH + k]));
    } else {
      val = 0xFFFF0000u;  // sentinel (never matches; replay-stale safe)
    }
    hx[i] = val;
  }
}

#define TAGMASK 0xFFFF0000FFFF0000ull

// 64 blocks x 256 threads (4 waves). Block b: group g=b>>3 (16 batch rows),
// col-slice s=b&7 (64 cols, both gates) -> ONE chain-phase per step (R9
// lesson: per-phase latency is a fixed ~2us regardless of prefetch depth;
// minimize phases/step). Group cliques of 8 blocks are independent: no
// cross-group straggler coupling. Fused tag16+fp16 dword protocol (R7):
// the cooperative tagged read IS the flag poll AND the payload fetch.
__global__ __launch_bounds__(256, 1) void ligru_mfma(
    const float* __restrict__ wx, const __half* __restrict__ u16,
    const float* __restrict__ ht, const float* __restrict__ mask,
    float* __restrict__ out, unsigned* __restrict__ hx) {
  const int tid = threadIdx.x;
  const int lane = tid & 63;
  const int w = tid >> 6;
  const int l15 = lane & 15;
  const int q = lane >> 4;
  const int b = blockIdx.x;
  const int g = b >> 3;
  const int s = b & 7;
  const int row0 = g * 16;
  const int j = s * 64 + w * 16 + l15;  // this lane's hidden col

  __shared__ alignas(16) char hsm[2][16 * 1024];  // [par][m][k] fp16, XOR-swz

  // B-frags (u), persistent (128 VGPR). nt0: gate row j (at); nt1: row 512+j.
  f16x8 bf[KB][2];
#pragma unroll
  for (int kb = 0; kb < KB; ++kb) {
    bf[kb][0] = *(const f16x8*)(u16 + (size_t)j * HH + kb * 32 + q * 8);
    bf[kb][1] = *(const f16x8*)(u16 + (size_t)(HH + j) * HH + kb * 32 + q * 8);
  }

  // per-lane persistent state: rows m=4q+r, col j; fp32 master h
  float hreg[4], mreg[4];
#pragma unroll
  for (int r = 0; r < 4; ++r) {
    size_t off = (size_t)(row0 + 4 * q + r) * HH + j;
    mreg[r] = mask[off];
    hreg[r] = ht[off];
  }

  const size_t BTH = (size_t)BB * TT * HH;
  float* out_h = out;
  float* out_z = out + BTH;
  float* out_a = out + 2 * BTH;
  float* out_hc = out + 3 * BTH;

  const u64* hxg = (const u64*)hx + ((size_t)g << 13);  // [2 par][4096 qw]

  // initial fetch: h(0), parity 0, written by prep with tag 0
  u64 qw[16];
#pragma unroll
  for (int pp = 0; pp < 16; ++pp)
    qw[pp] = __hip_atomic_load(hxg + pp * 256 + tid, __ATOMIC_RELAXED,
                               __HIP_MEMORY_SCOPE_AGENT);

  for (int t = 0; t < TT; ++t) {
    const int par = t & 1;

    // wx loads for this step (h-independent; in flight across the check)
    float wxa[4], wxz[4];
#pragma unroll
    for (int r = 0; r < 4; ++r) {
      size_t base = ((size_t)(row0 + 4 * q + r) * TT + t) * TWOH + j;
      wxa[r] = wx[base];
      wxz[r] = wx[base + HH];
    }

    // ---- tagged check + retry (first test is on the in-flight prefetch)
    {
      const u64* src = hxg + par * 4096 + tid;
      const u64 tagp =
          ((u64)(unsigned)t << 48) | ((u64)(unsigned)t << 16);
      bool ok = true;
#pragma unroll
      for (int pp = 0; pp < 16; ++pp) ok &= ((qw[pp] & TAGMASK) == tagp);
      int bail = 0;
      while (!__all(ok)) {
        __builtin_amdgcn_s_sleep(1);
#pragma unroll
        for (int pp = 0; pp < 16; ++pp)
          qw[pp] = __hip_atomic_load(src + pp * 256, __ATOMIC_RELAXED,
                                     __HIP_MEMORY_SCOPE_AGENT);
        ok = true;
#pragma unroll
        for (int pp = 0; pp < 16; ++pp) ok &= ((qw[pp] & TAGMASK) == tagp);
        if (++bail > (1 << 15)) break;
      }
    }

    // ---- stage payload halves into XOR-swizzled LDS
    {
      char* dst = hsm[par];
#pragma unroll
      for (int pp = 0; pp < 16; ++pp) {
        unsigned d0 = (unsigned)qw[pp], d1 = (unsigned)(qw[pp] >> 32);
        unsigned pk = (d0 & 0xFFFFu) | (d1 << 16);
        *(unsigned*)(dst + ((pp * 1024 + tid * 4) ^ ((pp & 7) << 4))) = pk;
      }
    }
    __syncthreads();

    // ---- prefetch next parity NOW (stale-tolerant; rides under MFMA+epi)
    if (t + 1 < TT) {
      const u64* srcn = hxg + (par ^ 1) * 4096 + tid;
#pragma unroll
      for (int pp = 0; pp < 16; ++pp)
        qw[pp] = __hip_atomic_load(srcn + pp * 256, __ATOMIC_RELAXED,
                                   __HIP_MEMORY_SCOPE_AGENT);
    }

    // ---- MFMA: A row=l15, k-chunk q from LDS; both gate tiles
    f32x4 acc0 = {0.f, 0.f, 0.f, 0.f}, acc1 = {0.f, 0.f, 0.f, 0.f};
#pragma unroll
    for (int kb = 0; kb < KB; ++kb) {
      int off = (l15 * 1024 + kb * 64 + q * 16) ^ ((l15 & 7) << 4);
      f16x8 af = *(const f16x8*)(hsm[par] + off);
      acc0 = __builtin_amdgcn_mfma_f32_16x16x32_f16(af, bf[kb][0], acc0, 0, 0, 0);
      acc1 = __builtin_amdgcn_mfma_f32_16x16x32_f16(af, bf[kb][1], acc1, 0, 0, 0);
    }

    // ---- epilogue: tagged per-dword h stores first (critical), outputs after
    unsigned* hd = hx + ((size_t)(g * 2 + (par ^ 1)) << 13);
    const unsigned tg = (unsigned)(t + 1) << 16;
    float atv[4], ztv[4], hcv[4];
#pragma unroll
    for (int r = 0; r < 4; ++r) {
      float at = acc0[r] + wxa[r];
      float zp = acc1[r] + wxz[r];
      float zt = 1.f / (1.f + __expf(-zp));
      float hc = fmaxf(at, 0.f) * mreg[r];
      float hn = hreg[r] * zt + (1.f - zt) * hc;
      hreg[r] = hn;
      __hip_atomic_store(hd + (4 * q + r) * HH + j,
                         tg | (unsigned)__half_as_ushort(__float2half(hn)),
                         __ATOMIC_RELAXED, __HIP_MEMORY_SCOPE_AGENT);
      atv[r] = at;
      ztv[r] = zt;
      hcv[r] = hc;
    }
#pragma unroll
    for (int r = 0; r < 4; ++r) {
      size_t oi = ((size_t)(row0 + 4 * q + r) * TT + t) * HH + j;
      __builtin_nontemporal_store(hreg[r], &out_h[oi]);
      __builtin_nontemporal_store(ztv[r], &out_z[oi]);
      __builtin_nontemporal_store(atv[r], &out_a[oi]);
      __builtin_nontemporal_store(hcv[r], &out_hc[oi]);
    }
    // hsm[par^1] is written next step only after this step's barrier: the
    // stage for step t+1 happens after every wave passed step t's sync.
  }
}

extern "C" void kernel_launch(void* const* d_in, const int* in_sizes, int n_in,
                              void* d_out, int out_size, void* d_ws,
                              size_t ws_size, hipStream_t stream) {
  const float* wx = (const float*)d_in[0];
  const float* u = (const float*)d_in[1];
  const float* ht = (const float*)d_in[2];
  const float* mask = (const float*)d_in[3];
  float* out = (float*)d_out;

  __half* u16 = (__half*)d_ws;
  unsigned* hx = (unsigned*)(u16 + WS_U16_HALVES);

  hipLaunchKernelGGL(prep_kernel, dim3(2048), dim3(256), 0, stream, u, ht, u16,
                     hx);
  hipLaunchKernelGGL(ligru_mfma, dim3(64), dim3(256), 0, stream, wx, u16, ht,
                     mask, out, hx);
}